// Round 5
// baseline (77.593 us; speedup 1.0000x reference)
//
#include <hip/hip_runtime.h>

#define TIMESTEPS 1000
#define NROWS 16384                 // 64 batch * 256 H rows
#define ROWS_PER_WAVE 2
#define WAVES_PER_BLOCK 4
#define NBLOCKS (NROWS / (ROWS_PER_WAVE * WAVES_PER_BLOCK))   // 2048
#define TOTAL_ELEMS 16384000.0      // 64 * 1 * 256 * 1000

// Wave-synchronous, single 1024-bin region per wave (4 KiB), R/T alternated
// with monotonically increasing generation tags:
//   gen 1 = R row0, gen 2 = T row0, gen 3 = R row1, gen 4 = T row1.
// Bin entry = (gen<<8)|w; atomicMax makes newer gens win, so no re-zeroing.
// Decode for gen g: w = max(v - (g<<8), 0) -> stale/empty read as 0, exactly
// the reference's zero-init bins (col 0 also decodes to 0 = reference max).
// Decoded R row (16 ints/lane) is held in registers across the T pass.
// 4 KiB bins/wave (vs 8 KiB in R4) -> 16 KiB/block -> up to 2x occupancy.
// All DS ops from one wave execute in order; wave_barrier pins compiler order.
// Accumulation is pure int (exact: per-lane <= 32*255^2 ~ 2.1e6).

__device__ __forceinline__ void scatter_row(
    int* __restrict__ binw, const float4& x, int base, int lane)
{
#pragma unroll
    for (int j = 0; j < 4; ++j) {
        const float v = (&x.x)[j];
        const int   w = lane * 4 + j;          // column index, <= 255
        // q = (int(x*1000) - 1) mod 1000, x==0 dropped. f32 mul + trunc
        // matches jnp astype(int32); q in [-1, 998] for x in [0,1).
        int q = (int)(v * 1000.0f) - 1;
        if (q < 0) q += TIMESTEPS;
        if (v != 0.0f) atomicMax(&binw[q], base | w);
    }
}

__global__ __launch_bounds__(256, 8) void holo_row_loss(
    const float* __restrict__ rec,
    const float* __restrict__ tgt,
    double* __restrict__ block_partials)
{
    __shared__ int bins[WAVES_PER_BLOCK][1024];   // 16 KiB
    __shared__ int wave_sums[WAVES_PER_BLOCK];

    const int tid  = threadIdx.x;
    const int wav  = tid >> 6;
    const int lane = tid & 63;
    const int gw   = blockIdx.x * WAVES_PER_BLOCK + wav;   // global wave id

    int* __restrict__ binw = &bins[wav][0];
    const int4* __restrict__ bin4 = (const int4*)binw;

    // one-time zero (gen 0): 4 x int4 per lane
    int4 z4; z4.x = 0; z4.y = 0; z4.z = 0; z4.w = 0;
    int4* zb = (int4*)binw;
#pragma unroll
    for (int j = 0; j < 4; ++j) zb[j * 64 + lane] = z4;

    const float4* rec4 = (const float4*)rec;
    const float4* tgt4 = (const float4*)tgt;
    const int row0 = gw * ROWS_PER_WAVE;

    // prefetch row 0 only (row 1 is software-pipelined to keep VGPRs low)
    const float4 xr0 = rec4[row0 * 64 + lane];
    const float4 xt0 = tgt4[row0 * 64 + lane];
    __builtin_amdgcn_wave_barrier();

    int s = 0;
    int wr[16];

    // ---------------- row 0 ----------------
    scatter_row(binw, xr0, 1 << 8, lane);        // gen 1 = R row0
    __builtin_amdgcn_wave_barrier();

    // issue row-1 global loads here: latency hides under row-0 DS/VALU work
    const float4 xr1 = rec4[(row0 + 1) * 64 + lane];
    const float4 xt1 = tgt4[(row0 + 1) * 64 + lane];

    // read + decode R row0 into registers
#pragma unroll
    for (int k = 0; k < 4; ++k) {
        const int4 a = bin4[k * 64 + lane];
        wr[k * 4 + 0] = max(a.x - (1 << 8), 0);
        wr[k * 4 + 1] = max(a.y - (1 << 8), 0);
        wr[k * 4 + 2] = max(a.z - (1 << 8), 0);
        wr[k * 4 + 3] = max(a.w - (1 << 8), 0);
    }
    __builtin_amdgcn_wave_barrier();

    scatter_row(binw, xt0, 2 << 8, lane);        // gen 2 = T row0
    __builtin_amdgcn_wave_barrier();

#pragma unroll
    for (int k = 0; k < 4; ++k) {
        const int4 b = bin4[k * 64 + lane];
        const int d0 = wr[k * 4 + 0] - max(b.x - (2 << 8), 0);
        const int d1 = wr[k * 4 + 1] - max(b.y - (2 << 8), 0);
        const int d2 = wr[k * 4 + 2] - max(b.z - (2 << 8), 0);
        const int d3 = wr[k * 4 + 3] - max(b.w - (2 << 8), 0);
        s += d0 * d0; s += d1 * d1; s += d2 * d2; s += d3 * d3;
    }
    __builtin_amdgcn_wave_barrier();

    // ---------------- row 1 ----------------
    scatter_row(binw, xr1, 3 << 8, lane);        // gen 3 = R row1
    __builtin_amdgcn_wave_barrier();

#pragma unroll
    for (int k = 0; k < 4; ++k) {
        const int4 a = bin4[k * 64 + lane];
        wr[k * 4 + 0] = max(a.x - (3 << 8), 0);
        wr[k * 4 + 1] = max(a.y - (3 << 8), 0);
        wr[k * 4 + 2] = max(a.z - (3 << 8), 0);
        wr[k * 4 + 3] = max(a.w - (3 << 8), 0);
    }
    __builtin_amdgcn_wave_barrier();

    scatter_row(binw, xt1, 4 << 8, lane);        // gen 4 = T row1
    __builtin_amdgcn_wave_barrier();

#pragma unroll
    for (int k = 0; k < 4; ++k) {
        const int4 b = bin4[k * 64 + lane];
        const int d0 = wr[k * 4 + 0] - max(b.x - (4 << 8), 0);
        const int d1 = wr[k * 4 + 1] - max(b.y - (4 << 8), 0);
        const int d2 = wr[k * 4 + 2] - max(b.z - (4 << 8), 0);
        const int d3 = wr[k * 4 + 3] - max(b.w - (4 << 8), 0);
        s += d0 * d0; s += d1 * d1; s += d2 * d2; s += d3 * d3;
    }

    // wave reduce (int, exact), then one double per block
    for (int off = 32; off > 0; off >>= 1) s += __shfl_down(s, off, 64);
    if (lane == 0) wave_sums[wav] = s;
    __syncthreads();
    if (tid == 0) {
        const long long bsum = (long long)wave_sums[0] + wave_sums[1]
                             + (long long)wave_sums[2] + wave_sums[3];
        block_partials[blockIdx.x] = (double)bsum;
    }
}

// Deterministic final reduction: 2048 doubles, 8 independent loads/thread.
__global__ __launch_bounds__(256) void reduce_partials(
    const double* __restrict__ block_partials,
    float* __restrict__ out)
{
    __shared__ double wave_sums[4];
    const int tid = threadIdx.x;
    double s = 0.0;
#pragma unroll
    for (int i = 0; i < NBLOCKS / 256; ++i)
        s += block_partials[i * 256 + tid];
    for (int off = 32; off > 0; off >>= 1) s += __shfl_down(s, off, 64);
    if ((tid & 63) == 0) wave_sums[tid >> 6] = s;
    __syncthreads();
    if (tid == 0) {
        double tot = wave_sums[0] + wave_sums[1] + wave_sums[2] + wave_sums[3];
        out[0] = (float)(tot / TOTAL_ELEMS);
    }
}

extern "C" void kernel_launch(void* const* d_in, const int* in_sizes, int n_in,
                              void* d_out, int out_size, void* d_ws, size_t ws_size,
                              hipStream_t stream)
{
    const float* rec = (const float*)d_in[0];
    const float* tgt = (const float*)d_in[1];
    float* out = (float*)d_out;
    double* block_partials = (double*)d_ws;    // NBLOCKS * 8 = 16 KiB

    holo_row_loss<<<NBLOCKS, 256, 0, stream>>>(rec, tgt, block_partials);
    reduce_partials<<<1, 256, 0, stream>>>(block_partials, out);
}